// Round 8
// baseline (1911.456 us; speedup 1.0000x reference)
//
#include <hip/hip_runtime.h>
#include <stdint.h>

typedef unsigned short u16;
typedef unsigned int u32;
typedef short short8 __attribute__((ext_vector_type(8)));
typedef float f32x4 __attribute__((ext_vector_type(4)));

struct LevelTab {
  int Hf[5], Wf[5], Hp[5], Wp[5], HW[5], M[5], mtcum[5], aoff[5];
  long xoffp[5], moff[5], ppcum[5], mcum[5];
  float asize[5], astride[5];
};

__device__ __forceinline__ u16 f2bf(float f) {
  u32 u = __float_as_uint(f);
  u = (u + 0x7fffu + ((u >> 16) & 1u)) >> 16;
  return (u16)u;
}
__device__ __forceinline__ float bflo(u32 v) { return __uint_as_float(v << 16); }
__device__ __forceinline__ float bfhi(u32 v) { return __uint_as_float(v & 0xffff0000u); }

__device__ __forceinline__ void gload16(const void* g, void* l) {
  __builtin_amdgcn_global_load_lds((__attribute__((address_space(1))) void*)(g),
                                   (__attribute__((address_space(3))) void*)(l),
                                   16, 0, 0);
}

// ---------------- weight prep ----------------
__global__ __launch_bounds__(256) void prep_tower_w(const float* __restrict__ cls_tw,
                                                    const float* __restrict__ reg_tw,
                                                    u16* __restrict__ W2t) {
  long t = (long)blockIdx.x * 256 + threadIdx.x;
  const long total = 2L * 4 * 256 * 2304;
  if (t >= total) return;
  int ci = (int)(t & 255);
  long u = t >> 8;
  int j = (int)(u % 9); u /= 9;
  int co = (int)(u & 255); u >>= 8;
  int layer = (int)(u & 3);
  int tw = (int)(u >> 2);
  const float* src = tw ? reg_tw : cls_tw;
  float v = src[(((long)layer * 256 + co) * 256 + ci) * 9 + j];
  W2t[t] = f2bf(v);
}

__global__ __launch_bounds__(256) void prep_cls_w(const float* __restrict__ cls_hw,
                                                  u16* __restrict__ W2c) {
  long t = (long)blockIdx.x * 256 + threadIdx.x;
  if (t >= 128L * 2304) return;
  int ci = (int)(t & 255);
  long u = t >> 8;
  int j = (int)(u % 9);
  int co = (int)(u / 9);
  float v = (co < 80) ? cls_hw[(((long)co * 256 + ci) * 9 + j)] : 0.f;
  W2c[t] = f2bf(v);
}

__global__ __launch_bounds__(256) void prep_reg_w(const float* __restrict__ reg_hw,
                                                  const float* __restrict__ iou_hw,
                                                  u16* __restrict__ W2r) {
  long t = (long)blockIdx.x * 256 + threadIdx.x;
  if (t >= 5L * 2304) return;
  int ci = (int)(t & 255);
  long u = t >> 8;
  int j = (int)(u % 9);
  int o = (int)(u / 9);
  float v = (o < 4) ? reg_hw[(((long)o * 256 + ci) * 9 + j)] : iou_hw[(long)ci * 9 + j];
  W2r[t] = f2bf(v);
}

// ---------------- input convert: NCHW fp32 -> padded NHWC bf16 ----------------
// Borders are zeroed ONCE here for all four ping-pong buffers; gn_fused writes
// interior pixels only, so borders stay zero for every layer.
__global__ __launch_bounds__(256) void convert_in(const float* __restrict__ i0, const float* __restrict__ i1,
                                                  const float* __restrict__ i2, const float* __restrict__ i3,
                                                  const float* __restrict__ i4, u16* __restrict__ X0,
                                                  u16* __restrict__ Z1, u16* __restrict__ Z2,
                                                  u16* __restrict__ Z3, LevelTab lt) {
  long t = (long)blockIdx.x * 256 + threadIdx.x;
  if (t >= lt.ppcum[4] * 32) return;
  const int c8 = (int)(t & 31);
  long pp = t >> 5;
  int lvl = 0;
#pragma unroll
  for (int i = 0; i < 4; ++i) lvl += (pp >= lt.ppcum[i]);
  const long lp = pp - (lvl ? lt.ppcum[lvl - 1] : 0);
  const int Hp = lt.Hp[lvl], Wp = lt.Wp[lvl], Wf = lt.Wf[lvl], HW = lt.HW[lvl];
  const int HpWp = Hp * Wp;
  const int n = (int)(lp / HpWp);
  const int rem = (int)(lp - (long)n * HpWp);
  const int yp = rem / Wp, xp = rem - yp * Wp;
  const long oof = (lt.xoffp[lvl] + lp) * 256 + c8 * 8;
  if (yp == 0 || yp == Hp - 1 || xp == 0 || xp == Wp - 1) {
    const uint4 z = make_uint4(0u, 0u, 0u, 0u);
    *(uint4*)(X0 + oof) = z;
    *(uint4*)(Z1 + oof) = z;
    *(uint4*)(Z2 + oof) = z;
    *(uint4*)(Z3 + oof) = z;
    return;
  }
  const float* src = lvl == 0 ? i0 : lvl == 1 ? i1 : lvl == 2 ? i2 : lvl == 3 ? i3 : i4;
  const int y = yp - 1, x = xp - 1;
  const long sb = ((long)n * 256 + c8 * 8) * HW + (long)y * Wf + x;
  u32 o4[4];
#pragma unroll
  for (int i = 0; i < 4; ++i) {
    float f0 = src[sb + (long)(2 * i) * HW];
    float f1 = src[sb + (long)(2 * i + 1) * HW];
    o4[i] = (u32)f2bf(f0) | ((u32)f2bf(f1) << 16);
  }
  *(uint4*)(X0 + oof) = make_uint4(o4[0], o4[1], o4[2], o4[3]);
}

// ---------------- conv (implicit GEMM, MFMA, 3-deep LDS + double frag regs) ----------------
// 128x128 tile, 4 waves. MODE 0: merged dual-path, path = TOP HALF of swizzled grid
// (keeps each XCD on one input buffer for L2 locality). NP in {1,2}.
// MODE 1: cls head -> fp32 d_out[b*8525+aoff+p][85] at +5..85, col<80.
template <int MODE>
__global__ __launch_bounds__(256, 2) void conv_mfma(
    const u16* __restrict__ XpadA, const u16* __restrict__ XpadB,
    const u16* __restrict__ W2A, const u16* __restrict__ W2B,
    const float* __restrict__ biasA, const float* __restrict__ biasB,
    u16* __restrict__ OtmpA, u16* __restrict__ OtmpB,
    float* __restrict__ Oout, int NP, LevelTab lt) {
  __shared__ __align__(16) u16 sA[3][128 * 32];
  __shared__ __align__(16) u16 sB[3][128 * 32];

  // bijective XCD-chunked swizzle (m204)
  const int nwg = gridDim.x;
  const int qq = nwg >> 3, rr = nwg & 7;
  const int xcd = blockIdx.x & 7, ib = blockIdx.x >> 3;
  const int sid = (xcd < rr ? xcd * (qq + 1) : rr * (qq + 1) + (xcd - rr) * qq) + ib;

  int path, tileId, nt;
  if (MODE == 0) {
    if (NP == 2) {
      const int half = nwg >> 1;
      path = (sid >= half) ? 1 : 0;
      const int inner = sid - path * half;
      tileId = inner >> 1;
      nt = inner & 1;
    } else {
      path = 0;
      tileId = sid >> 1;
      nt = sid & 1;
    }
  } else {
    path = 0;
    tileId = sid;
    nt = 0;
  }
  const u16* __restrict__ Xpad = path ? XpadB : XpadA;
  const u16* __restrict__ W2 = path ? W2B : W2A;
  const float* __restrict__ bias = path ? biasB : biasA;
  u16* __restrict__ Otmp = path ? OtmpB : OtmpA;

  int lvl = 0;
#pragma unroll
  for (int i = 0; i < 4; ++i) lvl += (tileId >= lt.mtcum[i]);
  const int mt = tileId - (lvl ? lt.mtcum[lvl - 1] : 0);
  const int Hp = lt.Hp[lvl], Wp = lt.Wp[lvl], Wf = lt.Wf[lvl];
  const int HW = lt.HW[lvl], M = lt.M[lvl];
  const long xbase = lt.xoffp[lvl] * 256;

  const int tid = threadIdx.x;
  const int w = tid >> 6, lane = tid & 63;
  const int rsub = lane >> 2;
  const int r0 = w * 16 + rsub;
  // source-chunk swizzle: LDS slot (row, s) holds global chunk (s - (row>>1))&3
  const int q2 = ((lane & 3) - ((lane >> 3) & 3)) & 3;

  long gA[2], gB[2];
#pragma unroll
  for (int i = 0; i < 2; ++i) {
    int ml = mt * 128 + r0 + i * 64;
    if (ml > M - 1) ml = M - 1;
    const int n = ml / HW;
    const int pr = ml - n * HW;
    const int y = pr / Wf;
    const int x = pr - y * Wf;
    gA[i] = xbase + ((long)((n * Hp + y) * Wp + x)) * 256 + q2 * 8;
    gB[i] = (long)(nt * 128 + r0 + i * 64) * 2304 + q2 * 8;
  }

  const int wm = w >> 1, wn = w & 1;
  const int lm = lane & 15;
  // read-side slot: chunk kg of row r lives at slot (kg + (r>>1))&3; per-lane constant
  const int slot8 = ((((lane >> 4) + ((lane >> 1) & 3)) & 3) << 3);

  f32x4 acc[4][4];
#pragma unroll
  for (int a = 0; a < 4; ++a)
#pragma unroll
    for (int c = 0; c < 4; ++c) acc[a][c] = {0.f, 0.f, 0.f, 0.f};

  auto STAGE = [&](int kk, int buf) {
    const int j = kk >> 3;
    const int c0 = (kk & 7) << 5;
    const int jy = j / 3, jx = j - jy * 3;
    const long aK = ((long)(jy * Wp + jx)) * 256 + c0;
    const long bK = (long)kk << 5;
    gload16(Xpad + gA[0] + aK, sA[buf] + w * 512);
    gload16(Xpad + gA[1] + aK, sA[buf] + 2048 + w * 512);
    gload16(W2 + gB[0] + bK, sB[buf] + w * 512);
    gload16(W2 + gB[1] + bK, sB[buf] + 2048 + w * 512);
  };

  short8 a0[4], b0[4], a1[4], b1[4];
  auto FRAG0 = [&](int cur) {
    const u16* pa = sA[cur];
    const u16* pb = sB[cur];
#pragma unroll
    for (int mi = 0; mi < 4; ++mi)
      a0[mi] = *(const short8*)(pa + ((wm * 64 + mi * 16 + lm) << 5) + slot8);
#pragma unroll
    for (int ni = 0; ni < 4; ++ni)
      b0[ni] = *(const short8*)(pb + ((wn * 64 + ni * 16 + lm) << 5) + slot8);
  };
  auto FRAG1 = [&](int cur) {
    const u16* pa = sA[cur];
    const u16* pb = sB[cur];
#pragma unroll
    for (int mi = 0; mi < 4; ++mi)
      a1[mi] = *(const short8*)(pa + ((wm * 64 + mi * 16 + lm) << 5) + slot8);
#pragma unroll
    for (int ni = 0; ni < 4; ++ni)
      b1[ni] = *(const short8*)(pb + ((wn * 64 + ni * 16 + lm) << 5) + slot8);
  };
  auto MFMA0 = [&]() {
    __builtin_amdgcn_s_setprio(1);
#pragma unroll
    for (int mi = 0; mi < 4; ++mi)
#pragma unroll
      for (int ni = 0; ni < 4; ++ni)
        acc[mi][ni] = __builtin_amdgcn_mfma_f32_16x16x32_bf16(a0[mi], b0[ni], acc[mi][ni], 0, 0, 0);
    __builtin_amdgcn_s_setprio(0);
  };
  auto MFMA1 = [&]() {
    __builtin_amdgcn_s_setprio(1);
#pragma unroll
    for (int mi = 0; mi < 4; ++mi)
#pragma unroll
      for (int ni = 0; ni < 4; ++ni)
        acc[mi][ni] = __builtin_amdgcn_mfma_f32_16x16x32_bf16(a1[mi], b1[ni], acc[mi][ni], 0, 0, 0);
    __builtin_amdgcn_s_setprio(0);
  };

  STAGE(0, 0);
  STAGE(1, 1);
  asm volatile("s_waitcnt vmcnt(4)" ::: "memory");
  __builtin_amdgcn_s_barrier();
  FRAG0(0);
  STAGE(2, 2);

  int rd = 1;
  int st = 0;
  for (int kk = 0; kk < 68; kk += 2) {
    asm volatile("s_waitcnt vmcnt(4)" ::: "memory");
    __builtin_amdgcn_s_barrier();
    FRAG1(rd);
    rd = rd == 2 ? 0 : rd + 1;
    STAGE(kk + 3, st);
    st = st == 2 ? 0 : st + 1;
    MFMA0();
    asm volatile("s_waitcnt vmcnt(4)" ::: "memory");
    __builtin_amdgcn_s_barrier();
    FRAG0(rd);
    rd = rd == 2 ? 0 : rd + 1;
    STAGE(kk + 4, st);
    st = st == 2 ? 0 : st + 1;
    MFMA1();
  }
  asm volatile("s_waitcnt vmcnt(4)" ::: "memory");
  __builtin_amdgcn_s_barrier();
  FRAG1(rd);
  rd = rd == 2 ? 0 : rd + 1;
  STAGE(71, st);
  MFMA0();
  asm volatile("s_waitcnt vmcnt(4)" ::: "memory");
  __builtin_amdgcn_s_barrier();
  FRAG0(rd);
  rd = rd == 2 ? 0 : rd + 1;
  MFMA1();
  asm volatile("s_waitcnt vmcnt(0)" ::: "memory");
  __builtin_amdgcn_s_barrier();
  FRAG1(rd);
  MFMA0();
  MFMA1();

  const int mwb = mt * 128 + wm * 64;
  const int colb = nt * 128 + wn * 64;
  const int rq4 = (lane >> 4) << 2;
#pragma unroll
  for (int ni = 0; ni < 4; ++ni) {
    const int col = colb + ni * 16 + lm;
    if (MODE == 1 && col >= 80) continue;
    const float bv = bias[col];
#pragma unroll
    for (int mi = 0; mi < 4; ++mi) {
      const int rb = mwb + mi * 16 + rq4;
#pragma unroll
      for (int rg = 0; rg < 4; ++rg) {
        const int ml = rb + rg;
        if (ml < M) {
          const float v = acc[mi][ni][rg] + bv;
          if (MODE == 0) {
            Otmp[(lt.moff[lvl] + ml) * 256 + col] = f2bf(v);
          } else {
            const int nb = ml / HW;
            const int pr = ml - nb * HW;
            Oout[((long)nb * 8525 + lt.aoff[lvl] + pr) * 85 + 5 + col] = v;
          }
        }
      }
    }
  }
}

// ---------------- fused GroupNorm (stats + apply + ReLU), interior-only writes ----------
// Block per (path,lvl,b,g); grid = NP*1280. Phase-1 reduction is bitwise-identical
// to the old gn_stats; phase-2 re-reads the (L2-hot) group slice and writes the
// padded interior. Borders were zeroed once by convert_in.
__global__ __launch_bounds__(256) void gn_fused(const u16* __restrict__ tmpA,
                                                const u16* __restrict__ tmpB,
                                                const float* __restrict__ gammaA,
                                                const float* __restrict__ betaA,
                                                const float* __restrict__ gammaB,
                                                const float* __restrict__ betaB,
                                                u16* __restrict__ poutA, u16* __restrict__ poutB,
                                                LevelTab lt) {
  const int bid = blockIdx.x;
  const int path = bid / 1280;
  const int lb = bid - path * 1280;
  const u16* __restrict__ tmp = path ? tmpB : tmpA;
  const float* __restrict__ gamma = path ? gammaB : gammaA;
  const float* __restrict__ beta = path ? betaB : betaA;
  u16* __restrict__ pout = path ? poutB : poutA;
  const int lvl = lb >> 8, bg = lb & 255, b = bg >> 5, g = bg & 31;
  const int HW = lt.HW[lvl];
  const long base = (lt.moff[lvl] + (long)b * HW) * 256 + g * 8;

  float s = 0.f, ss = 0.f;
  for (int p = threadIdx.x; p < HW; p += 256) {
    const uint4 r = *(const uint4*)(tmp + base + (long)p * 256);
    const u32 u[4] = {r.x, r.y, r.z, r.w};
#pragma unroll
    for (int i = 0; i < 4; ++i) {
      float f0 = bflo(u[i]), f1 = bfhi(u[i]);
      s += f0 + f1;
      ss += f0 * f0 + f1 * f1;
    }
  }
#pragma unroll
  for (int o = 32; o; o >>= 1) {
    s += __shfl_down(s, o);
    ss += __shfl_down(ss, o);
  }
  __shared__ float rs[4], rss[4];
  __shared__ float smean, srstd;
  const int w = threadIdx.x >> 6, lane = threadIdx.x & 63;
  if (lane == 0) { rs[w] = s; rss[w] = ss; }
  __syncthreads();
  if (threadIdx.x == 0) {
    s = rs[0] + rs[1] + rs[2] + rs[3];
    ss = rss[0] + rss[1] + rss[2] + rss[3];
    const float inv = 1.f / (float)(HW * 8);
    const float mean = s * inv;
    const float var = ss * inv - mean * mean;
    smean = mean;
    srstd = rsqrtf(var + 1e-5f);
  }
  __syncthreads();
  const float mean = smean, rstd = srstd;

  float gm[8], bt[8];
#pragma unroll
  for (int i = 0; i < 8; ++i) {
    gm[i] = gamma[g * 8 + i];
    bt[i] = beta[g * 8 + i];
  }
  const int Wf = lt.Wf[lvl], Wp = lt.Wp[lvl];
  const int HpWp = lt.Hp[lvl] * Wp;
  u16* pb = pout + (lt.xoffp[lvl] + (long)b * HpWp) * 256 + g * 8;
  for (int p = threadIdx.x; p < HW; p += 256) {
    const uint4 r = *(const uint4*)(tmp + base + (long)p * 256);
    const int y = p / Wf, x = p - y * Wf;
    const u32 u[4] = {r.x, r.y, r.z, r.w};
    u32 o4[4];
#pragma unroll
    for (int i = 0; i < 4; ++i) {
      float f0 = (bflo(u[i]) - mean) * rstd * gm[2 * i] + bt[2 * i];
      float f1 = (bfhi(u[i]) - mean) * rstd * gm[2 * i + 1] + bt[2 * i + 1];
      f0 = fmaxf(f0, 0.f);
      f1 = fmaxf(f1, 0.f);
      o4[i] = (u32)f2bf(f0) | ((u32)f2bf(f1) << 16);
    }
    *(uint4*)(pb + ((long)(y + 1) * Wp + (x + 1)) * 256) = make_uint4(o4[0], o4[1], o4[2], o4[3]);
  }
}

// ---------------- reg+iou heads + anchor decode: one wave per pixel ----------------
__global__ __launch_bounds__(256) void regiou_decode(const u16* __restrict__ Xp,
                                                     const u16* __restrict__ W2r,
                                                     const float* __restrict__ reg_hb,
                                                     const float* __restrict__ iou_hb,
                                                     const float* __restrict__ scales,
                                                     float* __restrict__ out, LevelTab lt) {
  const long gt = (long)blockIdx.x * 256 + threadIdx.x;
  const int gw = (int)(gt >> 6);
  const int lane = threadIdx.x & 63;
  if (gw >= (int)lt.mcum[4]) return;
  int lvl = 0;
#pragma unroll
  for (int i = 0; i < 4; ++i) lvl += (gw >= (int)lt.mcum[i]);
  const int m = gw - (int)(lvl ? lt.mcum[lvl - 1] : 0);
  const int HW = lt.HW[lvl], Wf = lt.Wf[lvl], Hp = lt.Hp[lvl], Wp = lt.Wp[lvl];
  const int b = m / HW, pr = m - b * HW;
  const int y = pr / Wf, x = pr - y * Wf;
  const long base = (lt.xoffp[lvl] + (long)(b * Hp + y) * Wp + x) * 256 + lane * 4;
  float acc[5] = {0.f, 0.f, 0.f, 0.f, 0.f};
#pragma unroll
  for (int j = 0; j < 9; ++j) {
    const int jy = j / 3, jx = j - jy * 3;
    const uint2 ar = *(const uint2*)(Xp + base + ((long)(jy * Wp + jx)) * 256);
    const float x0 = bflo(ar.x), x1 = bfhi(ar.x), x2 = bflo(ar.y), x3 = bfhi(ar.y);
#pragma unroll
    for (int o = 0; o < 5; ++o) {
      const uint2 wr = *(const uint2*)(W2r + o * 2304 + j * 256 + lane * 4);
      acc[o] += x0 * bflo(wr.x) + x1 * bfhi(wr.x) + x2 * bflo(wr.y) + x3 * bfhi(wr.y);
    }
  }
#pragma unroll
  for (int o = 0; o < 5; ++o)
#pragma unroll
    for (int d = 32; d; d >>= 1) acc[o] += __shfl_down(acc[o], d);
  if (lane == 0) {
    const float sc = scales[lvl];
    const float r0 = (acc[0] + reg_hb[0]) * sc;
    const float r1 = (acc[1] + reg_hb[1]) * sc;
    const float r2 = (acc[2] + reg_hb[2]) * sc;
    const float r3 = (acc[3] + reg_hb[3]) * sc;
    const float iou = acc[4] + iou_hb[0];
    const float st = lt.astride[lvl], sz = lt.asize[lvl];
    const float cx = (x + 0.5f) * st, cy = (y + 0.5f) * st;
    const float xx = r0 * sz + cx, yy = r1 * sz + cy;
    const float ww = expf(r2) * sz, hh = expf(r3) * sz;
    float* o = out + ((long)b * 8525 + lt.aoff[lvl] + pr) * 85;
    o[0] = xx - 0.5f * ww;
    o[1] = yy - 0.5f * hh;
    o[2] = xx + 0.5f * ww;
    o[3] = yy + 0.5f * hh;
    o[4] = iou;
  }
}

// ---------------- host ----------------
extern "C" void kernel_launch(void* const* d_in, const int* in_sizes, int n_in, void* d_out,
                              int out_size, void* d_ws, size_t ws_size, hipStream_t stream) {
  const float* feats[5];
  for (int i = 0; i < 5; ++i) feats[i] = (const float*)d_in[i];
  const float* cls_tw = (const float*)d_in[5];
  const float* cls_tb = (const float*)d_in[6];
  const float* cls_tg = (const float*)d_in[7];
  const float* cls_tbeta = (const float*)d_in[8];
  const float* reg_tw = (const float*)d_in[9];
  const float* reg_tb = (const float*)d_in[10];
  const float* reg_tg = (const float*)d_in[11];
  const float* reg_tbeta = (const float*)d_in[12];
  const float* cls_hw = (const float*)d_in[13];
  const float* cls_hb = (const float*)d_in[14];
  const float* reg_hw = (const float*)d_in[15];
  const float* reg_hb = (const float*)d_in[16];
  const float* iou_hw = (const float*)d_in[17];
  const float* iou_hb = (const float*)d_in[18];
  const float* scales = (const float*)d_in[19];
  float* out = (float*)d_out;

  LevelTab lt;
  const int Hs[5] = {80, 40, 20, 10, 5};
  const float sizes[5] = {32.f, 64.f, 128.f, 256.f, 512.f};
  const float strides[5] = {8.f, 16.f, 32.f, 64.f, 128.f};
  long ppc = 0, mc = 0;
  int mtc = 0, ao = 0;
  for (int i = 0; i < 5; ++i) {
    const int H = Hs[i];
    lt.Hf[i] = H; lt.Wf[i] = H; lt.Hp[i] = H + 2; lt.Wp[i] = H + 2;
    lt.HW[i] = H * H; lt.M[i] = 8 * H * H;
    lt.xoffp[i] = ppc; lt.moff[i] = mc; lt.aoff[i] = ao;
    ppc += 8L * (H + 2) * (H + 2);
    mc += lt.M[i];
    mtc += (lt.M[i] + 127) / 128;
    lt.ppcum[i] = ppc; lt.mcum[i] = mc; lt.mtcum[i] = mtc;
    ao += H * H;
    lt.asize[i] = sizes[i]; lt.astride[i] = strides[i];
  }

  char* ws = (char*)d_ws;
  size_t off = 0;
  auto take = [&](size_t bytes) {
    off = (off + 255) & ~(size_t)255;
    char* p = ws + off;
    off += bytes;
    return p;
  };
  auto alg = [](size_t v) { return (v + 255) & ~(size_t)255; };
  const size_t sizeX = alg((size_t)ppc * 512);
  const size_t sizeT = alg((size_t)mc * 512);
  const size_t wTsz = alg((size_t)2 * 4 * 256 * 2304 * 2);
  const size_t wCsz = alg((size_t)128 * 2304 * 2);
  const size_t wRsz = alg((size_t)5 * 2304 * 2);
  const size_t needMerged = 4 * sizeX + 2 * sizeT + wTsz + wCsz + wRsz + 4096;
  const bool MERGED = (ws_size >= needMerged);

  const int ppBlocks = (int)((ppc * 32 + 255) / 256);

  if (MERGED) {
    u16* X0 = (u16*)take(sizeX);
    u16* C1 = (u16*)take(sizeX);
    u16* R0 = (u16*)take(sizeX);
    u16* R1 = (u16*)take(sizeX);
    u16* tmpA = (u16*)take(sizeT);
    u16* tmpB = (u16*)take(sizeT);
    u16* W2t = (u16*)take(wTsz);
    u16* W2c = (u16*)take(wCsz);
    u16* W2r = (u16*)take(wRsz);

    prep_tower_w<<<(int)((2L * 4 * 256 * 2304 + 255) / 256), 256, 0, stream>>>(cls_tw, reg_tw, W2t);
    prep_cls_w<<<(int)((128L * 2304 + 255) / 256), 256, 0, stream>>>(cls_hw, W2c);
    prep_reg_w<<<(int)((5L * 2304 + 255) / 256), 256, 0, stream>>>(reg_hw, iou_hw, W2r);
    convert_in<<<ppBlocks, 256, 0, stream>>>(feats[0], feats[1], feats[2], feats[3], feats[4],
                                             X0, C1, R0, R1, lt);

    // pad buffers per path: cls writes {X0, C1} at layer {even, odd}; reg {R0, R1}
    u16* wrA[4] = {X0, C1, X0, C1};
    u16* wrB[4] = {R0, R1, R0, R1};
    const u16* curA = X0;
    const u16* curB = X0;
    for (int layer = 0; layer < 4; ++layer) {
      const u16* w2A = W2t + (size_t)(0 * 4 + layer) * 256 * 2304;
      const u16* w2B = W2t + (size_t)(1 * 4 + layer) * 256 * 2304;
      conv_mfma<0><<<mtc * 2 * 2, 256, 0, stream>>>(curA, curB, w2A, w2B,
                                                    cls_tb + layer * 256, reg_tb + layer * 256,
                                                    tmpA, tmpB, nullptr, 2, lt);
      gn_fused<<<2 * 1280, 256, 0, stream>>>(tmpA, tmpB,
                                             cls_tg + layer * 256, cls_tbeta + layer * 256,
                                             reg_tg + layer * 256, reg_tbeta + layer * 256,
                                             wrA[layer], wrB[layer], lt);
      curA = wrA[layer];
      curB = wrB[layer];
    }
    conv_mfma<1><<<mtc, 256, 0, stream>>>(curA, curA, W2c, W2c, cls_hb, cls_hb,
                                          nullptr, nullptr, out, 1, lt);
    regiou_decode<<<(int)((mc * 64 + 255) / 256), 256, 0, stream>>>(curB, W2r, reg_hb, iou_hb,
                                                                    scales, out, lt);
  } else {
    // sequential fallback
    u16* X0 = (u16*)take(sizeX);
    u16* padA = (u16*)take(sizeX);
    u16* padB = (u16*)take(sizeX);
    u16* tmp = (u16*)take(sizeT);
    u16* W2t = (u16*)take(wTsz);
    u16* W2c = (u16*)take(wCsz);
    u16* W2r = (u16*)take(wRsz);

    prep_tower_w<<<(int)((2L * 4 * 256 * 2304 + 255) / 256), 256, 0, stream>>>(cls_tw, reg_tw, W2t);
    prep_cls_w<<<(int)((128L * 2304 + 255) / 256), 256, 0, stream>>>(cls_hw, W2c);
    prep_reg_w<<<(int)((5L * 2304 + 255) / 256), 256, 0, stream>>>(reg_hw, iou_hw, W2r);
    convert_in<<<ppBlocks, 256, 0, stream>>>(feats[0], feats[1], feats[2], feats[3], feats[4],
                                             X0, padA, padB, padA, lt);

    u16* pads[2] = {padA, padB};
    for (int tw = 0; tw < 2; ++tw) {
      const float* tb = tw ? reg_tb : cls_tb;
      const float* tg = tw ? reg_tg : cls_tg;
      const float* tbe = tw ? reg_tbeta : cls_tbeta;
      const u16* cur = X0;
      for (int layer = 0; layer < 4; ++layer) {
        const u16* w2 = W2t + (size_t)(tw * 4 + layer) * 256 * 2304;
        conv_mfma<0><<<mtc * 2, 256, 0, stream>>>(cur, cur, w2, w2, tb + layer * 256,
                                                  tb + layer * 256, tmp, tmp, nullptr, 1, lt);
        u16* nxt = pads[layer & 1];
        gn_fused<<<1280, 256, 0, stream>>>(tmp, tmp, tg + layer * 256, tbe + layer * 256,
                                           tg + layer * 256, tbe + layer * 256, nxt, nxt, lt);
        cur = nxt;
      }
      if (tw == 0) {
        conv_mfma<1><<<mtc, 256, 0, stream>>>(cur, cur, W2c, W2c, cls_hb, cls_hb,
                                              nullptr, nullptr, out, 1, lt);
      } else {
        regiou_decode<<<(int)((mc * 64 + 255) / 256), 256, 0, stream>>>(cur, W2r, reg_hb, iou_hb,
                                                                        scales, out, lt);
      }
    }
  }
}

// Round 10
// 1342.970 us; speedup vs baseline: 1.4233x; 1.4233x over previous
//
#include <hip/hip_runtime.h>
#include <stdint.h>

typedef unsigned short u16;
typedef unsigned int u32;
typedef short short8 __attribute__((ext_vector_type(8)));
typedef float f32x4 __attribute__((ext_vector_type(4)));

#define GN_CHUNK 800
#define GN_MAXCH 8

struct LevelTab {
  int Hf[5], Wf[5], Hp[5], Wp[5], HW[5], M[5], mtcum[5], aoff[5];
  int gch[5];
  long xoffp[5], moff[5], ppcum[5], mcum[5];
  float asize[5], astride[5];
};

__device__ __forceinline__ u16 f2bf(float f) {
  u32 u = __float_as_uint(f);
  u = (u + 0x7fffu + ((u >> 16) & 1u)) >> 16;
  return (u16)u;
}
__device__ __forceinline__ float bflo(u32 v) { return __uint_as_float(v << 16); }
__device__ __forceinline__ float bfhi(u32 v) { return __uint_as_float(v & 0xffff0000u); }

__device__ __forceinline__ void gload16(const void* g, void* l) {
  __builtin_amdgcn_global_load_lds((__attribute__((address_space(1))) void*)(g),
                                   (__attribute__((address_space(3))) void*)(l),
                                   16, 0, 0);
}

// ---------------- weight prep ----------------
__global__ __launch_bounds__(256) void prep_tower_w(const float* __restrict__ cls_tw,
                                                    const float* __restrict__ reg_tw,
                                                    u16* __restrict__ W2t) {
  long t = (long)blockIdx.x * 256 + threadIdx.x;
  const long total = 2L * 4 * 256 * 2304;
  if (t >= total) return;
  int ci = (int)(t & 255);
  long u = t >> 8;
  int j = (int)(u % 9); u /= 9;
  int co = (int)(u & 255); u >>= 8;
  int layer = (int)(u & 3);
  int tw = (int)(u >> 2);
  const float* src = tw ? reg_tw : cls_tw;
  float v = src[(((long)layer * 256 + co) * 256 + ci) * 9 + j];
  W2t[t] = f2bf(v);
}

__global__ __launch_bounds__(256) void prep_cls_w(const float* __restrict__ cls_hw,
                                                  u16* __restrict__ W2c) {
  long t = (long)blockIdx.x * 256 + threadIdx.x;
  if (t >= 128L * 2304) return;
  int ci = (int)(t & 255);
  long u = t >> 8;
  int j = (int)(u % 9);
  int co = (int)(u / 9);
  float v = (co < 80) ? cls_hw[(((long)co * 256 + ci) * 9 + j)] : 0.f;
  W2c[t] = f2bf(v);
}

__global__ __launch_bounds__(256) void prep_reg_w(const float* __restrict__ reg_hw,
                                                  const float* __restrict__ iou_hw,
                                                  u16* __restrict__ W2r) {
  long t = (long)blockIdx.x * 256 + threadIdx.x;
  if (t >= 5L * 2304) return;
  int ci = (int)(t & 255);
  long u = t >> 8;
  int j = (int)(u % 9);
  int o = (int)(u / 9);
  float v = (o < 4) ? reg_hw[(((long)o * 256 + ci) * 9 + j)] : iou_hw[(long)ci * 9 + j];
  W2r[t] = f2bf(v);
}

// ---------------- input convert: NCHW fp32 -> padded NHWC bf16 (borders zero) ----------------
__global__ __launch_bounds__(256) void convert_in(const float* __restrict__ i0, const float* __restrict__ i1,
                                                  const float* __restrict__ i2, const float* __restrict__ i3,
                                                  const float* __restrict__ i4, u16* __restrict__ X0,
                                                  LevelTab lt) {
  long t = (long)blockIdx.x * 256 + threadIdx.x;
  if (t >= lt.ppcum[4] * 32) return;
  const int c8 = (int)(t & 31);
  long pp = t >> 5;
  int lvl = 0;
#pragma unroll
  for (int i = 0; i < 4; ++i) lvl += (pp >= lt.ppcum[i]);
  const long lp = pp - (lvl ? lt.ppcum[lvl - 1] : 0);
  const int Hp = lt.Hp[lvl], Wp = lt.Wp[lvl], Wf = lt.Wf[lvl], HW = lt.HW[lvl];
  const int HpWp = Hp * Wp;
  const int n = (int)(lp / HpWp);
  const int rem = (int)(lp - (long)n * HpWp);
  const int yp = rem / Wp, xp = rem - yp * Wp;
  u16* op = X0 + (lt.xoffp[lvl] + lp) * 256 + c8 * 8;
  if (yp == 0 || yp == Hp - 1 || xp == 0 || xp == Wp - 1) {
    *(uint4*)op = make_uint4(0u, 0u, 0u, 0u);
    return;
  }
  const float* src = lvl == 0 ? i0 : lvl == 1 ? i1 : lvl == 2 ? i2 : lvl == 3 ? i3 : i4;
  const int y = yp - 1, x = xp - 1;
  const long sb = ((long)n * 256 + c8 * 8) * HW + (long)y * Wf + x;
  u32 o4[4];
#pragma unroll
  for (int i = 0; i < 4; ++i) {
    float f0 = src[sb + (long)(2 * i) * HW];
    float f1 = src[sb + (long)(2 * i + 1) * HW];
    o4[i] = (u32)f2bf(f0) | ((u32)f2bf(f1) << 16);
  }
  *(uint4*)op = make_uint4(o4[0], o4[1], o4[2], o4[3]);
}

// ---------------- conv (implicit GEMM, MFMA, 3-deep LDS + double frag regs) ----------------
// 128x128 tile, 4 waves. MODE 0: merged dual-path, path = TOP HALF of swizzled grid
// (keeps each XCD on one input buffer for L2 locality). NP in {1,2}.
// MODE 1: cls head -> fp32 d_out[b*8525+aoff+p][85] at +5..85, col<80.
template <int MODE>
__global__ __launch_bounds__(256, 2) void conv_mfma(
    const u16* __restrict__ XpadA, const u16* __restrict__ XpadB,
    const u16* __restrict__ W2A, const u16* __restrict__ W2B,
    const float* __restrict__ biasA, const float* __restrict__ biasB,
    u16* __restrict__ OtmpA, u16* __restrict__ OtmpB,
    float* __restrict__ Oout, int NP, LevelTab lt) {
  __shared__ __align__(16) u16 sA[3][128 * 32];
  __shared__ __align__(16) u16 sB[3][128 * 32];

  // bijective XCD-chunked swizzle (m204)
  const int nwg = gridDim.x;
  const int qq = nwg >> 3, rr = nwg & 7;
  const int xcd = blockIdx.x & 7, ib = blockIdx.x >> 3;
  const int sid = (xcd < rr ? xcd * (qq + 1) : rr * (qq + 1) + (xcd - rr) * qq) + ib;

  int path, tileId, nt;
  if (MODE == 0) {
    if (NP == 2) {
      const int half = nwg >> 1;
      path = (sid >= half) ? 1 : 0;
      const int inner = sid - path * half;
      tileId = inner >> 1;
      nt = inner & 1;
    } else {
      path = 0;
      tileId = sid >> 1;
      nt = sid & 1;
    }
  } else {
    path = 0;
    tileId = sid;
    nt = 0;
  }
  const u16* __restrict__ Xpad = path ? XpadB : XpadA;
  const u16* __restrict__ W2 = path ? W2B : W2A;
  const float* __restrict__ bias = path ? biasB : biasA;
  u16* __restrict__ Otmp = path ? OtmpB : OtmpA;

  int lvl = 0;
#pragma unroll
  for (int i = 0; i < 4; ++i) lvl += (tileId >= lt.mtcum[i]);
  const int mt = tileId - (lvl ? lt.mtcum[lvl - 1] : 0);
  const int Hp = lt.Hp[lvl], Wp = lt.Wp[lvl], Wf = lt.Wf[lvl];
  const int HW = lt.HW[lvl], M = lt.M[lvl];
  const long xbase = lt.xoffp[lvl] * 256;

  const int tid = threadIdx.x;
  const int w = tid >> 6, lane = tid & 63;
  const int rsub = lane >> 2;
  const int r0 = w * 16 + rsub;
  // source-chunk swizzle: LDS slot (row, s) holds global chunk (s - (row>>1))&3
  const int q2 = ((lane & 3) - ((lane >> 3) & 3)) & 3;

  long gA[2], gB[2];
#pragma unroll
  for (int i = 0; i < 2; ++i) {
    int ml = mt * 128 + r0 + i * 64;
    if (ml > M - 1) ml = M - 1;
    const int n = ml / HW;
    const int pr = ml - n * HW;
    const int y = pr / Wf;
    const int x = pr - y * Wf;
    gA[i] = xbase + ((long)((n * Hp + y) * Wp + x)) * 256 + q2 * 8;
    gB[i] = (long)(nt * 128 + r0 + i * 64) * 2304 + q2 * 8;
  }

  const int wm = w >> 1, wn = w & 1;
  const int lm = lane & 15;
  // read-side slot: chunk kg of row r lives at slot (kg + (r>>1))&3; per-lane constant
  const int slot8 = ((((lane >> 4) + ((lane >> 1) & 3)) & 3) << 3);

  f32x4 acc[4][4];
#pragma unroll
  for (int a = 0; a < 4; ++a)
#pragma unroll
    for (int c = 0; c < 4; ++c) acc[a][c] = {0.f, 0.f, 0.f, 0.f};

  auto STAGE = [&](int kk, int buf) {
    const int j = kk >> 3;
    const int c0 = (kk & 7) << 5;
    const int jy = j / 3, jx = j - jy * 3;
    const long aK = ((long)(jy * Wp + jx)) * 256 + c0;
    const long bK = (long)kk << 5;
    gload16(Xpad + gA[0] + aK, sA[buf] + w * 512);
    gload16(Xpad + gA[1] + aK, sA[buf] + 2048 + w * 512);
    gload16(W2 + gB[0] + bK, sB[buf] + w * 512);
    gload16(W2 + gB[1] + bK, sB[buf] + 2048 + w * 512);
  };

  short8 a0[4], b0[4], a1[4], b1[4];
  auto FRAG0 = [&](int cur) {
    const u16* pa = sA[cur];
    const u16* pb = sB[cur];
#pragma unroll
    for (int mi = 0; mi < 4; ++mi)
      a0[mi] = *(const short8*)(pa + ((wm * 64 + mi * 16 + lm) << 5) + slot8);
#pragma unroll
    for (int ni = 0; ni < 4; ++ni)
      b0[ni] = *(const short8*)(pb + ((wn * 64 + ni * 16 + lm) << 5) + slot8);
  };
  auto FRAG1 = [&](int cur) {
    const u16* pa = sA[cur];
    const u16* pb = sB[cur];
#pragma unroll
    for (int mi = 0; mi < 4; ++mi)
      a1[mi] = *(const short8*)(pa + ((wm * 64 + mi * 16 + lm) << 5) + slot8);
#pragma unroll
    for (int ni = 0; ni < 4; ++ni)
      b1[ni] = *(const short8*)(pb + ((wn * 64 + ni * 16 + lm) << 5) + slot8);
  };
  auto MFMA0 = [&]() {
    __builtin_amdgcn_s_setprio(1);
#pragma unroll
    for (int mi = 0; mi < 4; ++mi)
#pragma unroll
      for (int ni = 0; ni < 4; ++ni)
        acc[mi][ni] = __builtin_amdgcn_mfma_f32_16x16x32_bf16(a0[mi], b0[ni], acc[mi][ni], 0, 0, 0);
    __builtin_amdgcn_s_setprio(0);
  };
  auto MFMA1 = [&]() {
    __builtin_amdgcn_s_setprio(1);
#pragma unroll
    for (int mi = 0; mi < 4; ++mi)
#pragma unroll
      for (int ni = 0; ni < 4; ++ni)
        acc[mi][ni] = __builtin_amdgcn_mfma_f32_16x16x32_bf16(a1[mi], b1[ni], acc[mi][ni], 0, 0, 0);
    __builtin_amdgcn_s_setprio(0);
  };

  STAGE(0, 0);
  STAGE(1, 1);
  asm volatile("s_waitcnt vmcnt(4)" ::: "memory");
  __builtin_amdgcn_s_barrier();
  FRAG0(0);
  STAGE(2, 2);

  int rd = 1;
  int st = 0;
  for (int kk = 0; kk < 68; kk += 2) {
    asm volatile("s_waitcnt vmcnt(4)" ::: "memory");
    __builtin_amdgcn_s_barrier();
    FRAG1(rd);
    rd = rd == 2 ? 0 : rd + 1;
    STAGE(kk + 3, st);
    st = st == 2 ? 0 : st + 1;
    MFMA0();
    asm volatile("s_waitcnt vmcnt(4)" ::: "memory");
    __builtin_amdgcn_s_barrier();
    FRAG0(rd);
    rd = rd == 2 ? 0 : rd + 1;
    STAGE(kk + 4, st);
    st = st == 2 ? 0 : st + 1;
    MFMA1();
  }
  asm volatile("s_waitcnt vmcnt(4)" ::: "memory");
  __builtin_amdgcn_s_barrier();
  FRAG1(rd);
  rd = rd == 2 ? 0 : rd + 1;
  STAGE(71, st);
  MFMA0();
  asm volatile("s_waitcnt vmcnt(4)" ::: "memory");
  __builtin_amdgcn_s_barrier();
  FRAG0(rd);
  rd = rd == 2 ? 0 : rd + 1;
  MFMA1();
  asm volatile("s_waitcnt vmcnt(0)" ::: "memory");
  __builtin_amdgcn_s_barrier();
  FRAG1(rd);
  MFMA0();
  MFMA1();

  const int mwb = mt * 128 + wm * 64;
  const int colb = nt * 128 + wn * 64;
  const int rq4 = (lane >> 4) << 2;
#pragma unroll
  for (int ni = 0; ni < 4; ++ni) {
    const int col = colb + ni * 16 + lm;
    if (MODE == 1 && col >= 80) continue;
    const float bv = bias[col];
#pragma unroll
    for (int mi = 0; mi < 4; ++mi) {
      const int rb = mwb + mi * 16 + rq4;
#pragma unroll
      for (int rg = 0; rg < 4; ++rg) {
        const int ml = rb + rg;
        if (ml < M) {
          const float v = acc[mi][ni][rg] + bv;
          if (MODE == 0) {
            Otmp[(lt.moff[lvl] + ml) * 256 + col] = f2bf(v);
          } else {
            const int nb = ml / HW;
            const int pr = ml - nb * HW;
            Oout[((long)nb * 8525 + lt.aoff[lvl] + pr) * 85 + 5 + col] = v;
          }
        }
      }
    }
  }
}

// ---------------- GN partial sums: coalesced, deterministic ----------------
// Block per (path,lvl,b,chunk). Threads: c8 = tid&31 (== group), po = tid>>5.
// Reads full 512B channel rows (uint4/lane, coalesced). Writes 64 floats/block
// to a private slot: part[((path*1280 + lvl*256 + b*32 + g)*GN_MAXCH + chunk)*2 + {0,1}].
__global__ __launch_bounds__(256) void gn_part(const u16* __restrict__ tmpA,
                                               const u16* __restrict__ tmpB,
                                               float* __restrict__ part, int perPath,
                                               LevelTab lt) {
  const int bid = blockIdx.x;
  const int path = bid / perPath;
  int r = bid - path * perPath;
  int lvl = 0;
#pragma unroll
  for (int i = 0; i < 4; ++i) {
    const int c = 8 * lt.gch[i];
    if (r >= c) { r -= c; lvl = i + 1; } else break;
  }
  const int b = r / lt.gch[lvl];
  const int chunk = r - b * lt.gch[lvl];
  const u16* __restrict__ tmp = path ? tmpB : tmpA;
  const int HW = lt.HW[lvl];
  const int start = chunk * GN_CHUNK;
  const int end = (start + GN_CHUNK < HW) ? start + GN_CHUNK : HW;

  const int tid = threadIdx.x;
  const int c8 = tid & 31, po = tid >> 5;
  const long base = (lt.moff[lvl] + (long)b * HW) * 256 + c8 * 8;
  float s = 0.f, ss = 0.f;
  for (int p = start + po; p < end; p += 8) {
    const uint4 r4 = *(const uint4*)(tmp + base + (long)p * 256);
    const u32 u[4] = {r4.x, r4.y, r4.z, r4.w};
#pragma unroll
    for (int i = 0; i < 4; ++i) {
      float f0 = bflo(u[i]), f1 = bfhi(u[i]);
      s += f0 + f1;
      ss += f0 * f0 + f1 * f1;
    }
  }
  // combine the two po values within each wave (lanes 0-31 <- +lanes 32-63)
  s += __shfl_down(s, 32);
  ss += __shfl_down(ss, 32);
  __shared__ float rs[4][32], rss[4][32];
  const int w = tid >> 6, lane = tid & 63;
  if (lane < 32) { rs[w][lane] = s; rss[w][lane] = ss; }
  __syncthreads();
  if (tid < 32) {
    const float S = rs[0][tid] + rs[1][tid] + rs[2][tid] + rs[3][tid];
    const float SS = rss[0][tid] + rss[1][tid] + rss[2][tid] + rss[3][tid];
    const long slot = ((long)((path * 1280 + lvl * 256 + b * 32 + tid) * GN_MAXCH + chunk)) * 2;
    part[slot] = S;
    part[slot + 1] = SS;
  }
}

// ---------------- GN finalize: 2*1280 (path,lvl,b,g) entries -> mean/rstd ----------------
__global__ __launch_bounds__(256) void gn_final(const float* __restrict__ part,
                                                float* __restrict__ stats, LevelTab lt) {
  const int idx = blockIdx.x * 256 + threadIdx.x;
  if (idx >= 2 * 1280) return;
  const int lb = idx % 1280;  // FIXED: was idx & 1279 (1280 not a power of two)
  const int lvl = lb >> 8;
  const int nch = lt.gch[lvl];
  float s = 0.f, ss = 0.f;
  const long sbase = (long)idx * GN_MAXCH * 2;
  for (int c = 0; c < nch; ++c) {
    s += part[sbase + c * 2];
    ss += part[sbase + c * 2 + 1];
  }
  const float inv = 1.f / (float)(lt.HW[lvl] * 8);
  const float mean = s * inv;
  const float var = ss * inv - mean * mean;
  stats[idx * 2 + 0] = mean;
  stats[idx * 2 + 1] = rsqrtf(var + 1e-5f);
}

// ---------------- GN apply + ReLU -> padded bf16 (borders zero); grid = NP*ppBlocks ----------------
__global__ __launch_bounds__(256) void gn_apply(const u16* __restrict__ tmpA,
                                                const u16* __restrict__ tmpB,
                                                const float* __restrict__ stats,
                                                const float* __restrict__ gammaA,
                                                const float* __restrict__ betaA,
                                                const float* __restrict__ gammaB,
                                                const float* __restrict__ betaB,
                                                u16* __restrict__ poutA, u16* __restrict__ poutB,
                                                int ppBlocks, LevelTab lt) {
  const int path = blockIdx.x / ppBlocks;
  const int xb = blockIdx.x - path * ppBlocks;
  const u16* __restrict__ tmp = path ? tmpB : tmpA;
  const float* __restrict__ gamma = path ? gammaB : gammaA;
  const float* __restrict__ beta = path ? betaB : betaA;
  u16* __restrict__ pout = path ? poutB : poutA;

  long t = (long)xb * 256 + threadIdx.x;
  if (t >= lt.ppcum[4] * 32) return;
  const int c8 = (int)(t & 31);
  long pp = t >> 5;
  int lvl = 0;
#pragma unroll
  for (int i = 0; i < 4; ++i) lvl += (pp >= lt.ppcum[i]);
  const long lp = pp - (lvl ? lt.ppcum[lvl - 1] : 0);
  const int Hp = lt.Hp[lvl], Wp = lt.Wp[lvl], Wf = lt.Wf[lvl], HW = lt.HW[lvl];
  const int HpWp = Hp * Wp;
  const int n = (int)(lp / HpWp);
  const int rem = (int)(lp - (long)n * HpWp);
  const int yp = rem / Wp, xp = rem - yp * Wp;
  u16* op = pout + (lt.xoffp[lvl] + lp) * 256 + c8 * 8;
  if (yp == 0 || yp == Hp - 1 || xp == 0 || xp == Wp - 1) {
    *(uint4*)op = make_uint4(0u, 0u, 0u, 0u);
    return;
  }
  const long m = lt.moff[lvl] + (long)n * HW + (long)(yp - 1) * Wf + (xp - 1);
  const uint4 r = *(const uint4*)(tmp + m * 256 + c8 * 8);
  const int sidx = (path * 1280 + lvl * 256 + n * 32 + c8) * 2;
  const float mean = stats[sidx], rstd = stats[sidx + 1];
  const u32 u[4] = {r.x, r.y, r.z, r.w};
  u32 o4[4];
#pragma unroll
  for (int i = 0; i < 4; ++i) {
    const int c = c8 * 8 + i * 2;
    float f0 = (bflo(u[i]) - mean) * rstd * gamma[c] + beta[c];
    float f1 = (bfhi(u[i]) - mean) * rstd * gamma[c + 1] + beta[c + 1];
    f0 = fmaxf(f0, 0.f);
    f1 = fmaxf(f1, 0.f);
    o4[i] = (u32)f2bf(f0) | ((u32)f2bf(f1) << 16);
  }
  *(uint4*)op = make_uint4(o4[0], o4[1], o4[2], o4[3]);
}

// ---------------- reg+iou heads + anchor decode: one wave per pixel ----------------
__global__ __launch_bounds__(256) void regiou_decode(const u16* __restrict__ Xp,
                                                     const u16* __restrict__ W2r,
                                                     const float* __restrict__ reg_hb,
                                                     const float* __restrict__ iou_hb,
                                                     const float* __restrict__ scales,
                                                     float* __restrict__ out, LevelTab lt) {
  const long gt = (long)blockIdx.x * 256 + threadIdx.x;
  const int gw = (int)(gt >> 6);
  const int lane = threadIdx.x & 63;
  if (gw >= (int)lt.mcum[4]) return;
  int lvl = 0;
#pragma unroll
  for (int i = 0; i < 4; ++i) lvl += (gw >= (int)lt.mcum[i]);
  const int m = gw - (int)(lvl ? lt.mcum[lvl - 1] : 0);
  const int HW = lt.HW[lvl], Wf = lt.Wf[lvl], Hp = lt.Hp[lvl], Wp = lt.Wp[lvl];
  const int b = m / HW, pr = m - b * HW;
  const int y = pr / Wf, x = pr - y * Wf;
  const long base = (lt.xoffp[lvl] + (long)(b * Hp + y) * Wp + x) * 256 + lane * 4;
  float acc[5] = {0.f, 0.f, 0.f, 0.f, 0.f};
#pragma unroll
  for (int j = 0; j < 9; ++j) {
    const int jy = j / 3, jx = j - jy * 3;
    const uint2 ar = *(const uint2*)(Xp + base + ((long)(jy * Wp + jx)) * 256);
    const float x0 = bflo(ar.x), x1 = bfhi(ar.x), x2 = bflo(ar.y), x3 = bfhi(ar.y);
#pragma unroll
    for (int o = 0; o < 5; ++o) {
      const uint2 wr = *(const uint2*)(W2r + o * 2304 + j * 256 + lane * 4);
      acc[o] += x0 * bflo(wr.x) + x1 * bfhi(wr.x) + x2 * bflo(wr.y) + x3 * bfhi(wr.y);
    }
  }
#pragma unroll
  for (int o = 0; o < 5; ++o)
#pragma unroll
    for (int d = 32; d; d >>= 1) acc[o] += __shfl_down(acc[o], d);
  if (lane == 0) {
    const float sc = scales[lvl];
    const float r0 = (acc[0] + reg_hb[0]) * sc;
    const float r1 = (acc[1] + reg_hb[1]) * sc;
    const float r2 = (acc[2] + reg_hb[2]) * sc;
    const float r3 = (acc[3] + reg_hb[3]) * sc;
    const float iou = acc[4] + iou_hb[0];
    const float st = lt.astride[lvl], sz = lt.asize[lvl];
    const float cx = (x + 0.5f) * st, cy = (y + 0.5f) * st;
    const float xx = r0 * sz + cx, yy = r1 * sz + cy;
    const float ww = expf(r2) * sz, hh = expf(r3) * sz;
    float* o = out + ((long)b * 8525 + lt.aoff[lvl] + pr) * 85;
    o[0] = xx - 0.5f * ww;
    o[1] = yy - 0.5f * hh;
    o[2] = xx + 0.5f * ww;
    o[3] = yy + 0.5f * hh;
    o[4] = iou;
  }
}

// ---------------- host ----------------
extern "C" void kernel_launch(void* const* d_in, const int* in_sizes, int n_in, void* d_out,
                              int out_size, void* d_ws, size_t ws_size, hipStream_t stream) {
  const float* feats[5];
  for (int i = 0; i < 5; ++i) feats[i] = (const float*)d_in[i];
  const float* cls_tw = (const float*)d_in[5];
  const float* cls_tb = (const float*)d_in[6];
  const float* cls_tg = (const float*)d_in[7];
  const float* cls_tbeta = (const float*)d_in[8];
  const float* reg_tw = (const float*)d_in[9];
  const float* reg_tb = (const float*)d_in[10];
  const float* reg_tg = (const float*)d_in[11];
  const float* reg_tbeta = (const float*)d_in[12];
  const float* cls_hw = (const float*)d_in[13];
  const float* cls_hb = (const float*)d_in[14];
  const float* reg_hw = (const float*)d_in[15];
  const float* reg_hb = (const float*)d_in[16];
  const float* iou_hw = (const float*)d_in[17];
  const float* iou_hb = (const float*)d_in[18];
  const float* scales = (const float*)d_in[19];
  float* out = (float*)d_out;

  LevelTab lt;
  const int Hs[5] = {80, 40, 20, 10, 5};
  const float sizes[5] = {32.f, 64.f, 128.f, 256.f, 512.f};
  const float strides[5] = {8.f, 16.f, 32.f, 64.f, 128.f};
  long ppc = 0, mc = 0;
  int mtc = 0, ao = 0, chTot = 0;
  for (int i = 0; i < 5; ++i) {
    const int H = Hs[i];
    lt.Hf[i] = H; lt.Wf[i] = H; lt.Hp[i] = H + 2; lt.Wp[i] = H + 2;
    lt.HW[i] = H * H; lt.M[i] = 8 * H * H;
    lt.gch[i] = (H * H + GN_CHUNK - 1) / GN_CHUNK;
    lt.xoffp[i] = ppc; lt.moff[i] = mc; lt.aoff[i] = ao;
    ppc += 8L * (H + 2) * (H + 2);
    mc += lt.M[i];
    mtc += (lt.M[i] + 127) / 128;
    lt.ppcum[i] = ppc; lt.mcum[i] = mc; lt.mtcum[i] = mtc;
    ao += H * H;
    chTot += lt.gch[i];
    lt.asize[i] = sizes[i]; lt.astride[i] = strides[i];
  }
  const int perPath = 8 * chTot;  // gn_part blocks per path

  char* ws = (char*)d_ws;
  size_t off = 0;
  auto take = [&](size_t bytes) {
    off = (off + 255) & ~(size_t)255;
    char* p = ws + off;
    off += bytes;
    return p;
  };
  auto alg = [](size_t v) { return (v + 255) & ~(size_t)255; };
  const size_t sizeX = alg((size_t)ppc * 512);
  const size_t sizeT = alg((size_t)mc * 512);
  const size_t wTsz = alg((size_t)2 * 4 * 256 * 2304 * 2);
  const size_t wCsz = alg((size_t)128 * 2304 * 2);
  const size_t wRsz = alg((size_t)5 * 2304 * 2);
  const size_t pSz = alg((size_t)2 * 1280 * GN_MAXCH * 2 * 4);
  const size_t sSz = alg((size_t)2 * 1280 * 2 * 4);
  const size_t needMerged = 4 * sizeX + 2 * sizeT + wTsz + wCsz + wRsz + pSz + sSz + 4096;
  const bool MERGED = (ws_size >= needMerged);

  const int ppBlocks = (int)((ppc * 32 + 255) / 256);

  if (MERGED) {
    u16* X0 = (u16*)take(sizeX);
    u16* C1 = (u16*)take(sizeX);
    u16* R0 = (u16*)take(sizeX);
    u16* R1 = (u16*)take(sizeX);
    u16* tmpA = (u16*)take(sizeT);
    u16* tmpB = (u16*)take(sizeT);
    u16* W2t = (u16*)take(wTsz);
    u16* W2c = (u16*)take(wCsz);
    u16* W2r = (u16*)take(wRsz);
    float* part = (float*)take(pSz);
    float* stats = (float*)take(sSz);

    prep_tower_w<<<(int)((2L * 4 * 256 * 2304 + 255) / 256), 256, 0, stream>>>(cls_tw, reg_tw, W2t);
    prep_cls_w<<<(int)((128L * 2304 + 255) / 256), 256, 0, stream>>>(cls_hw, W2c);
    prep_reg_w<<<(int)((5L * 2304 + 255) / 256), 256, 0, stream>>>(reg_hw, iou_hw, W2r);
    convert_in<<<ppBlocks, 256, 0, stream>>>(feats[0], feats[1], feats[2], feats[3], feats[4],
                                             X0, lt);

    // pad buffers per path: cls writes {X0, C1} at layer {even, odd}; reg {R0, R1}
    u16* wrA[4] = {X0, C1, X0, C1};
    u16* wrB[4] = {R0, R1, R0, R1};
    const u16* curA = X0;
    const u16* curB = X0;
    for (int layer = 0; layer < 4; ++layer) {
      const u16* w2A = W2t + (size_t)(0 * 4 + layer) * 256 * 2304;
      const u16* w2B = W2t + (size_t)(1 * 4 + layer) * 256 * 2304;
      conv_mfma<0><<<mtc * 2 * 2, 256, 0, stream>>>(curA, curB, w2A, w2B,
                                                    cls_tb + layer * 256, reg_tb + layer * 256,
                                                    tmpA, tmpB, nullptr, 2, lt);
      gn_part<<<2 * perPath, 256, 0, stream>>>(tmpA, tmpB, part, perPath, lt);
      gn_final<<<10, 256, 0, stream>>>(part, stats, lt);
      gn_apply<<<2 * ppBlocks, 256, 0, stream>>>(tmpA, tmpB, stats,
                                                 cls_tg + layer * 256, cls_tbeta + layer * 256,
                                                 reg_tg + layer * 256, reg_tbeta + layer * 256,
                                                 wrA[layer], wrB[layer], ppBlocks, lt);
      curA = wrA[layer];
      curB = wrB[layer];
    }
    conv_mfma<1><<<mtc, 256, 0, stream>>>(curA, curA, W2c, W2c, cls_hb, cls_hb,
                                          nullptr, nullptr, out, 1, lt);
    regiou_decode<<<(int)((mc * 64 + 255) / 256), 256, 0, stream>>>(curB, W2r, reg_hb, iou_hb,
                                                                    scales, out, lt);
  } else {
    // sequential fallback
    u16* X0 = (u16*)take(sizeX);
    u16* padA = (u16*)take(sizeX);
    u16* padB = (u16*)take(sizeX);
    u16* tmp = (u16*)take(sizeT);
    u16* W2t = (u16*)take(wTsz);
    u16* W2c = (u16*)take(wCsz);
    u16* W2r = (u16*)take(wRsz);
    float* part = (float*)take(pSz);
    float* stats = (float*)take(sSz);

    prep_tower_w<<<(int)((2L * 4 * 256 * 2304 + 255) / 256), 256, 0, stream>>>(cls_tw, reg_tw, W2t);
    prep_cls_w<<<(int)((128L * 2304 + 255) / 256), 256, 0, stream>>>(cls_hw, W2c);
    prep_reg_w<<<(int)((5L * 2304 + 255) / 256), 256, 0, stream>>>(reg_hw, iou_hw, W2r);
    convert_in<<<ppBlocks, 256, 0, stream>>>(feats[0], feats[1], feats[2], feats[3], feats[4],
                                             X0, lt);

    u16* pads[2] = {padA, padB};
    for (int tw = 0; tw < 2; ++tw) {
      const float* tb = tw ? reg_tb : cls_tb;
      const float* tg = tw ? reg_tg : cls_tg;
      const float* tbe = tw ? reg_tbeta : cls_tbeta;
      const u16* cur = X0;
      for (int layer = 0; layer < 4; ++layer) {
        const u16* w2 = W2t + (size_t)(tw * 4 + layer) * 256 * 2304;
        conv_mfma<0><<<mtc * 2, 256, 0, stream>>>(cur, cur, w2, w2, tb + layer * 256,
                                                  tb + layer * 256, tmp, tmp, nullptr, 1, lt);
        gn_part<<<perPath, 256, 0, stream>>>(tmp, tmp, part, perPath, lt);
        gn_final<<<10, 256, 0, stream>>>(part, stats, lt);
        u16* nxt = pads[layer & 1];
        gn_apply<<<ppBlocks, 256, 0, stream>>>(tmp, tmp, stats, tg + layer * 256,
                                               tbe + layer * 256, tg + layer * 256,
                                               tbe + layer * 256, nxt, nxt, ppBlocks, lt);
        cur = nxt;
      }
      if (tw == 0) {
        conv_mfma<1><<<mtc, 256, 0, stream>>>(cur, cur, W2c, W2c, cls_hb, cls_hb,
                                              nullptr, nullptr, out, 1, lt);
      } else {
        regiou_decode<<<(int)((mc * 64 + 255) / 256), 256, 0, stream>>>(cur, W2r, reg_hb, iou_hb,
                                                                        scales, out, lt);
      }
    }
  }
}